// Round 6
// baseline (2414.580 us; speedup 1.0000x reference)
//
#include <hip/hip_runtime.h>
#include <math.h>

#define SEQ    197
#define BATCH  32
#define ROWS   (BATCH * SEQ)      // 6304
#define MPAD   6400               // padded row count
#define DIM    512
#define NHEADS 8
#define NDEPTH 12
#define MLPD   2048
#define PKD    448                // patch K padded (432 real), 7 x 64
#define SP     208                // padded seq for attention (13 x 16)
#define PSTR   224                // Pm col stride (7 x 32)
#define VSTR   228                // Vt LDS row stride
#define EPSF   1e-5f

typedef unsigned short ushort_t;
typedef __attribute__((ext_vector_type(8))) short  short8;
typedef __attribute__((ext_vector_type(4))) float  floatx4;

__device__ __forceinline__ float bf2f(ushort_t u) {
    union { unsigned int i; float f; } v; v.i = ((unsigned int)u) << 16; return v.f;
}
__device__ __forceinline__ ushort_t f2bf(float f) {
    union { float f; unsigned int i; } v; v.f = f;
    unsigned int r = v.i + 0x7fffu + ((v.i >> 16) & 1u);
    return (ushort_t)(r >> 16);
}
__device__ __forceinline__ void gl2lds16(const ushort_t* g, ushort_t* l) {
    __builtin_amdgcn_global_load_lds(
        (const __attribute__((address_space(1))) unsigned int*)g,
        (__attribute__((address_space(3))) unsigned int*)l, 16, 0, 0);
}
__device__ __forceinline__ float gelu_tanh(float v) {
    const float y = 0.7978845608028654f * fmaf(0.044715f * v, v * v, v);
    const float e = __expf(-2.f * fabsf(y));
    const float th = copysignf((1.f - e) * __builtin_amdgcn_rcpf(1.f + e), y);
    return 0.5f * v * (1.f + th);
}

// ---------------------------------------------------------------------------
// Weight transpose + fp32->bf16: Wt[l][n][k] = bf16(W[l][k][n])
// ---------------------------------------------------------------------------
__global__ __launch_bounds__(256) void wtrans_kernel(
    const float* __restrict__ W, ushort_t* __restrict__ Wt, int K, int N)
{
    const int l = blockIdx.z;
    W  += (size_t)l * K * N;
    Wt += (size_t)l * K * N;
    const int n0 = blockIdx.x * 32;
    const int k0 = blockIdx.y * 32;
    const int t = threadIdx.x;

    __shared__ float tile[32][33];
    {
        const int row = t >> 3;
        const int cq  = (t & 7) * 4;
        const float4 v = *(const float4*)(W + (size_t)(k0 + row) * N + n0 + cq);
        tile[row][cq + 0] = v.x;
        tile[row][cq + 1] = v.y;
        tile[row][cq + 2] = v.z;
        tile[row][cq + 3] = v.w;
    }
    __syncthreads();
    {
        const int n  = t >> 3;
        const int kq = (t & 7) * 4;
        ushort4 o;
        o.x = f2bf(tile[kq + 0][n]);
        o.y = f2bf(tile[kq + 1][n]);
        o.z = f2bf(tile[kq + 2][n]);
        o.w = f2bf(tile[kq + 3][n]);
        *(ushort4*)(Wt + (size_t)(n0 + n) * K + k0 + kq) = o;
    }
}

// ---------------------------------------------------------------------------
// patch_w [432][512] -> pwt [512][448] bf16 (k >= 432 zero)
// ---------------------------------------------------------------------------
__global__ __launch_bounds__(256) void pwt_kernel(
    const float* __restrict__ pw, ushort_t* __restrict__ pwt)
{
    const int n = blockIdx.x;
    for (int k = threadIdx.x; k < PKD; k += 256)
        pwt[(size_t)n * PKD + k] = (k < 432) ? f2bf(pw[(size_t)k * DIM + n]) : (ushort_t)0;
}

// ---------------------------------------------------------------------------
// im2col: pcol[row][448] bf16.
// ---------------------------------------------------------------------------
__global__ __launch_bounds__(256) void im2col_kernel(
    const float* __restrict__ img, ushort_t* __restrict__ pcol)
{
    const int r = blockIdx.x;
    const int t = threadIdx.x;
    ushort_t* row = pcol + (size_t)r * PKD;
    const int b = r / SEQ;
    const int s = r - b * SEQ;
    const bool valid = (r < ROWS) && (s > 0);
    const int p = s - 1;
    const int gy = p / 14, gx = p - (p / 14) * 14;

    #pragma unroll
    for (int rep = 0; rep < 2; ++rep) {
        const int e = t + rep * 256;
        if (e >= PKD) break;
        float v = 0.f;
        if (valid && e < 432) {
            const int c = e / 144;
            const int rr = e - c * 144;
            const int fy = rr / 12, fx = rr - (rr / 12) * 12;
            const int py = gy * 8 - 2 + fy;
            const int px = gx * 8 - 2 + fx;
            if (py >= 0 && py < 112 && px >= 0 && px < 112)
                v = img[((size_t)(b * 3 + c) * 112 + py) * 112 + px];
        }
        row[e] = f2bf(v);
    }
}

// ---------------------------------------------------------------------------
// pos add + layer-0 ln1 fused: x = patch_acc (+cls) + pos; hb = bf16(LN(x))
// ---------------------------------------------------------------------------
__global__ __launch_bounds__(256) void pos_add_ln_kernel(
    float* __restrict__ x, const float* __restrict__ cls,
    const float* __restrict__ pos, ushort_t* __restrict__ hb,
    const float* __restrict__ g, const float* __restrict__ bta)
{
    const int r = blockIdx.x;
    const int t = threadIdx.x;
    const int b = r / SEQ;
    const int s = r - b * SEQ;
    float* xr = x + (size_t)r * DIM;
    const float* pr = pos + (size_t)s * DIM;
    float v0, v1;
    if (s == 0) {
        v0 = cls[t]       + pr[t];
        v1 = cls[t + 256] + pr[t + 256];
    } else {
        v0 = xr[t]       + pr[t];
        v1 = xr[t + 256] + pr[t + 256];
    }
    xr[t] = v0;
    xr[t + 256] = v1;
    float sm = v0 + v1;
    float ss = v0 * v0 + v1 * v1;
    #pragma unroll
    for (int off = 32; off > 0; off >>= 1) {
        sm += __shfl_xor(sm, off);
        ss += __shfl_xor(ss, off);
    }
    __shared__ float rs[4], rss[4];
    if ((t & 63) == 0) { rs[t >> 6] = sm; rss[t >> 6] = ss; }
    __syncthreads();
    sm = rs[0] + rs[1] + rs[2] + rs[3];
    ss = rss[0] + rss[1] + rss[2] + rss[3];
    const float mu  = sm * (1.f / 512.f);
    const float var = ss * (1.f / 512.f) - mu * mu;
    const float inv = rsqrtf(var + EPSF);
    ushort_t* op = hb + (size_t)r * DIM;
    op[t]       = f2bf((v0 - mu) * inv * g[t]       + bta[t]);
    op[t + 256] = f2bf((v1 - mu) * inv * g[t + 256] + bta[t + 256]);
}

// ---------------------------------------------------------------------------
// Fast LayerNorm: 4 rows/block, one wave per row, bf16 out.
// ---------------------------------------------------------------------------
__global__ __launch_bounds__(256) void ln4_kernel(
    const float* __restrict__ in, ushort_t* __restrict__ out,
    const float* __restrict__ g, const float* __restrict__ bta)
{
    const int t = threadIdx.x;
    const int w = t >> 6, lane = t & 63;
    const int r = blockIdx.x * 4 + w;
    const int off = lane * 8;
    const float* ip = in + (size_t)r * DIM + off;
    const float4 a = *(const float4*)ip;
    const float4 c = *(const float4*)(ip + 4);
    float s  = a.x + a.y + a.z + a.w + c.x + c.y + c.z + c.w;
    float ss = a.x*a.x + a.y*a.y + a.z*a.z + a.w*a.w + c.x*c.x + c.y*c.y + c.z*c.z + c.w*c.w;
    #pragma unroll
    for (int o = 32; o > 0; o >>= 1) {
        s  += __shfl_xor(s, o);
        ss += __shfl_xor(ss, o);
    }
    const float mu  = s * (1.f / 512.f);
    const float var = ss * (1.f / 512.f) - mu * mu;
    const float inv = rsqrtf(var + EPSF);
    const float4 g0 = *(const float4*)(g + off);
    const float4 g1 = *(const float4*)(g + off + 4);
    const float4 b0 = *(const float4*)(bta + off);
    const float4 b1 = *(const float4*)(bta + off + 4);
    ushort4 o0, o1;
    o0.x = f2bf((a.x - mu) * inv * g0.x + b0.x);
    o0.y = f2bf((a.y - mu) * inv * g0.y + b0.y);
    o0.z = f2bf((a.z - mu) * inv * g0.z + b0.z);
    o0.w = f2bf((a.w - mu) * inv * g0.w + b0.w);
    o1.x = f2bf((c.x - mu) * inv * g1.x + b1.x);
    o1.y = f2bf((c.y - mu) * inv * g1.y + b1.y);
    o1.z = f2bf((c.z - mu) * inv * g1.z + b1.z);
    o1.w = f2bf((c.w - mu) * inv * g1.w + b1.w);
    ushort_t* op = out + (size_t)r * DIM + off;
    *(ushort4*)op = o0;
    *(ushort4*)(op + 4) = o1;
}

// ---------------------------------------------------------------------------
// Row LayerNorm (final head LN; fp32 out)
// ---------------------------------------------------------------------------
__global__ __launch_bounds__(256) void ln_kernel(
    const float* __restrict__ in, float* __restrict__ out,
    const float* __restrict__ g, const float* __restrict__ bta,
    size_t in_stride, size_t out_stride)
{
    const int r = blockIdx.x;
    const int t = threadIdx.x;
    const float* ip = in + (size_t)r * in_stride;
    const float v0 = ip[t];
    const float v1 = ip[t + 256];
    float s = v0 + v1;
    float ss = v0 * v0 + v1 * v1;
    #pragma unroll
    for (int off = 32; off > 0; off >>= 1) {
        s  += __shfl_xor(s, off);
        ss += __shfl_xor(ss, off);
    }
    __shared__ float rs[4], rss[4];
    if ((t & 63) == 0) { rs[t >> 6] = s; rss[t >> 6] = ss; }
    __syncthreads();
    s  = rs[0] + rs[1] + rs[2] + rs[3];
    ss = rss[0] + rss[1] + rss[2] + rss[3];
    const float mu  = s * (1.f / 512.f);
    const float var = ss * (1.f / 512.f) - mu * mu;
    const float inv = rsqrtf(var + EPSF);
    float* op = out + (size_t)r * out_stride;
    op[t]       = (v0 - mu) * inv * g[t]       + bta[t];
    op[t + 256] = (v1 - mu) * inv * g[t + 256] + bta[t + 256];
}

// ---------------------------------------------------------------------------
// bf16 MFMA GEMM, compile-time shape. BK=64, XOR-swizzled LDS staging.
// MODE 0: Cb=bf16(acc+bias); 1: Cx+=acc+bias; 2: Cb=bf16(gelu); 3: Cx=acc+bias
// ---------------------------------------------------------------------------
template <int BM, int NN, int KK, int MODE>
__global__ __launch_bounds__(256) void gemm_bf16_kernel(
    const ushort_t* __restrict__ A, const ushort_t* __restrict__ Bt,
    const float* __restrict__ bias, ushort_t* __restrict__ Cb,
    float* __restrict__ Cx)
{
    constexpr int RA = BM / 4;
    constexpr int MI = BM / 32;
    __shared__ ushort_t As[BM * 64];
    __shared__ ushort_t Bs[128 * 64];
    const int t = threadIdx.x;
    const int l = t & 63;
    const int w = t >> 6;
    const int bm = blockIdx.y * BM;
    const int bn = blockIdx.x * 128;
    const int wm = (w & 1) * (BM / 2);
    const int wn = (w >> 1) * 64;

    const int srow = l >> 3;
    const int skw  = ((l & 7) ^ srow) * 8;
    const ushort_t* gA = A  + (size_t)(bm + w * RA + srow) * KK + skw;
    const ushort_t* gB = Bt + (size_t)(bn + w * 32 + srow) * KK + skw;

    floatx4 acc[MI][4];
    #pragma unroll
    for (int i = 0; i < MI; ++i)
        #pragma unroll
        for (int j = 0; j < 4; ++j)
            acc[i][j] = (floatx4){0.f, 0.f, 0.f, 0.f};

    const int fr = l & 15;
    const int quad = l >> 4;
    const int c0 = ((quad ^ (fr & 7)) * 8);

    #pragma unroll 4
    for (int k0 = 0; k0 < KK; k0 += 64) {
        #pragma unroll
        for (int jc = 0; jc < RA / 8; ++jc)
            gl2lds16(gA + (size_t)(jc * 8) * KK + k0, As + (w * RA + jc * 8) * 64);
        #pragma unroll
        for (int jc = 0; jc < 4; ++jc)
            gl2lds16(gB + (size_t)(jc * 8) * KK + k0, Bs + (w * 32 + jc * 8) * 64);
        __syncthreads();
        #pragma unroll
        for (int half = 0; half < 2; ++half) {
            const int co = c0 ^ (half * 32);
            short8 af[MI], bf4[4];
            #pragma unroll
            for (int i = 0; i < MI; ++i)
                af[i] = *(const short8*)(As + (wm + i * 16 + fr) * 64 + co);
            #pragma unroll
            for (int j = 0; j < 4; ++j)
                bf4[j] = *(const short8*)(Bs + (wn + j * 16 + fr) * 64 + co);
            #pragma unroll
            for (int i = 0; i < MI; ++i)
                #pragma unroll
                for (int j = 0; j < 4; ++j)
                    acc[i][j] = __builtin_amdgcn_mfma_f32_16x16x32_bf16(
                        af[i], bf4[j], acc[i][j], 0, 0, 0);
        }
        __syncthreads();
    }

    float bv[4];
    #pragma unroll
    for (int j = 0; j < 4; ++j)
        bv[j] = bias ? bias[bn + wn + j * 16 + fr] : 0.f;

    const int r0 = quad * 4;
    #pragma unroll
    for (int i = 0; i < MI; ++i)
        #pragma unroll
        for (int r = 0; r < 4; ++r) {
            const size_t row = (size_t)(bm + wm + i * 16 + r0 + r);
            if (MODE == 1) {
                float* cp = Cx + row * NN + bn + wn + fr;
                #pragma unroll
                for (int j = 0; j < 4; ++j)
                    cp[j * 16] += acc[i][j][r] + bv[j];
            } else if (MODE == 3) {
                float* cp = Cx + row * NN + bn + wn + fr;
                #pragma unroll
                for (int j = 0; j < 4; ++j)
                    cp[j * 16] = acc[i][j][r] + bv[j];
            } else if (MODE == 2) {
                ushort_t* cp = Cb + row * NN + bn + wn + fr;
                #pragma unroll
                for (int j = 0; j < 4; ++j)
                    cp[j * 16] = f2bf(gelu_tanh(acc[i][j][r] + bv[j]));
            } else {
                ushort_t* cp = Cb + row * NN + bn + wn + fr;
                #pragma unroll
                for (int j = 0; j < 4; ++j)
                    cp[j * 16] = f2bf(acc[i][j][r] + bv[j]);
            }
        }
}

// ---------------------------------------------------------------------------
// Fused QK^T + softmax + head-mix + LN(heads) -> Pm bf16 [b][g][208][224].
// Block per (i-tile of 16, b). Loops h staging K_h in swizzled LDS; probs
// kept in LDS bf16; mix+LN in-LDS; single global write of Pm.
// ---------------------------------------------------------------------------
__global__ __launch_bounds__(256) void qkmix_kernel(
    const ushort_t* __restrict__ qkv, const float* __restrict__ rw,
    const float* __restrict__ lw, const float* __restrict__ lb,
    ushort_t* __restrict__ Pm)
{
    const int it = blockIdx.x;        // 0..12
    const int b  = blockIdx.y;
    const int i0 = it * 16;
    const int t = threadIdx.x;
    const int w = t >> 6, lane = t & 63;
    const int fr = lane & 15, quad = lane >> 4;

    __shared__ ushort_t Ks[SP * 64];        // swizzled K_h
    __shared__ ushort_t Pl[8 * 16 * SP];    // probs [h][ii][j] bf16
    __shared__ float red_m[4][16], red_s[4][16];
    __shared__ float rws[64], lws[8], lbs[8];

    if (t < 64) rws[t] = rw[t];
    if (t < 8) { lws[t] = lw[t]; lbs[t] = lb[t]; }

    const size_t base = (size_t)(b * SEQ) * 1536;
    const size_t qrow = base + (size_t)(i0 + fr) * 1536;

    for (int h = 0; h < NHEADS; ++h) {
        __syncthreads();   // Ks reads of previous h done
        // stage K_h swizzled: LDS[r][c^(r&7)] = K[r][chunk c]
        for (int e = t; e < SP * 8; e += 256) {
            const int r = e >> 3;
            const int c = e & 7;
            *(short8*)(Ks + r * 64 + ((c ^ (r & 7)) * 8)) =
                *(const short8*)(qkv + base + (size_t)r * 1536 + 512 + h * 64 + c * 8);
        }
        __syncthreads();

        // A-frags (Q rows i0..i0+15) straight from global
        const short8 a0 = *(const short8*)(qkv + qrow + h * 64 + quad * 8);
        const short8 a1 = *(const short8*)(qkv + qrow + h * 64 + 32 + quad * 8);

        floatx4 acc[4];
        #pragma unroll
        for (int q = 0; q < 4; ++q) {
            const int nf = w + q * 4;
            acc[q] = (floatx4){0.f, 0.f, 0.f, 0.f};
            if (nf < 13) {
                const int row = nf * 16 + fr;
                const short8 b0 = *(const short8*)(Ks + row * 64 + ((quad ^ (fr & 7)) * 8));
                const short8 b1 = *(const short8*)(Ks + row * 64 + (((quad + 4) ^ (fr & 7)) * 8));
                acc[q] = __builtin_amdgcn_mfma_f32_16x16x32_bf16(a0, b0, acc[q], 0, 0, 0);
                acc[q] = __builtin_amdgcn_mfma_f32_16x16x32_bf16(a1, b1, acc[q], 0, 0, 0);
            }
        }

        // scale + mask, partial max over this wave's n-frags
        float pmax[4];
        #pragma unroll
        for (int rr = 0; rr < 4; ++rr) {
            float m = -1e30f;
            #pragma unroll
            for (int q = 0; q < 4; ++q) {
                const int nf = w + q * 4;
                const bool bad = (nf >= 13) || (nf == 12 && fr >= 5);
                const float v = bad ? -1e30f : acc[q][rr] * 0.125f;
                m = fmaxf(m, v);
            }
            #pragma unroll
            for (int off = 1; off < 16; off <<= 1) m = fmaxf(m, __shfl_xor(m, off));
            pmax[rr] = m;
        }
        if (fr == 0) {
            #pragma unroll
            for (int rr = 0; rr < 4; ++rr) red_m[w][quad * 4 + rr] = pmax[rr];
        }
        __syncthreads();

        float pe[4][4];   // [q][rr]
        #pragma unroll
        for (int rr = 0; rr < 4; ++rr) {
            const int row = quad * 4 + rr;
            const float mx = fmaxf(fmaxf(red_m[0][row], red_m[1][row]),
                                   fmaxf(red_m[2][row], red_m[3][row]));
            float s = 0.f;
            #pragma unroll
            for (int q = 0; q < 4; ++q) {
                const int nf = w + q * 4;
                const bool bad = (nf >= 13) || (nf == 12 && fr >= 5);
                const float v = bad ? 0.f : __expf(acc[q][rr] * 0.125f - mx);
                pe[q][rr] = v;
                s += v;
            }
            #pragma unroll
            for (int off = 1; off < 16; off <<= 1) s += __shfl_xor(s, off);
            if (fr == 0) red_s[w][row] = s;
        }
        __syncthreads();

        #pragma unroll
        for (int rr = 0; rr < 4; ++rr) {
            const int row = quad * 4 + rr;
            const float inv = 1.f / (red_s[0][row] + red_s[1][row] +
                                     red_s[2][row] + red_s[3][row]);
            #pragma unroll
            for (int q = 0; q < 4; ++q) {
                const int nf = w + q * 4;
                if (nf < 13)
                    Pl[h * (16 * SP) + row * SP + nf * 16 + fr] = f2bf(pe[q][rr] * inv);
            }
        }
    }
    __syncthreads();

    // head mix + LN over heads, in place Pl[h] -> Pl[g]
    for (int e = t; e < 16 * SP; e += 256) {
        const int ii = e / SP;
        const int j  = e - ii * SP;
        float a[8];
        #pragma unroll
        for (int h = 0; h < 8; ++h) a[h] = bf2f(Pl[h * (16 * SP) + ii * SP + j]);
        float m[8];
        float mu = 0.f;
        #pragma unroll
        for (int g = 0; g < 8; ++g) {
            float s = 0.f;
            #pragma unroll
            for (int h = 0; h < 8; ++h) s = fmaf(a[h], rws[h * 8 + g], s);
            m[g] = s;
            mu += s;
        }
        mu *= 0.125f;
        float var = 0.f;
        #pragma unroll
        for (int g = 0; g < 8; ++g) { const float d = m[g] - mu; var = fmaf(d, d, var); }
        var *= 0.125f;
        const float inv = rsqrtf(var + EPSF);
        #pragma unroll
        for (int g = 0; g < 8; ++g)
            Pl[g * (16 * SP) + ii * SP + j] = f2bf((m[g] - mu) * inv * lws[g] + lbs[g]);
    }
    __syncthreads();

    // write Pm (cols >= 208 zero; cols 197..207 already zero from mask)
    for (int e = t; e < 8 * 16 * PSTR; e += 256) {
        const int g = e / (16 * PSTR);
        const int rem = e - g * (16 * PSTR);
        const int ii = rem / PSTR;
        const int j = rem - ii * PSTR;
        const ushort_t v = (j < SP) ? Pl[g * (16 * SP) + ii * SP + j] : (ushort_t)0;
        Pm[(((size_t)(b * 8 + g)) * SP + i0 + ii) * PSTR + j] = v;
    }
}

// ---------------------------------------------------------------------------
// AV via MFMA: block per (b,g, i-half). O = Pm (rows) @ V.
// ---------------------------------------------------------------------------
__global__ __launch_bounds__(256) void av_kernel(
    const ushort_t* __restrict__ Pm, const ushort_t* __restrict__ qkv,
    ushort_t* __restrict__ o)
{
    const int bg = blockIdx.x;
    const int hf = blockIdx.y;
    const int b = bg >> 3, g = bg & 7;
    const int t = threadIdx.x;
    const int w = t >> 6, lane = t & 63;
    const int fr = lane & 15, quad = lane >> 4;
    const int cnt = hf ? 6 : 7;
    const int q0 = hf * 112;

    __shared__ ushort_t Vt[64 * VSTR];
    __shared__ ushort_t As[112 * 32];

    for (int e = t; e < 64 * VSTR / 4; e += 256)
        *(ushort4*)(Vt + e * 4) = (ushort4){0, 0, 0, 0};
    __syncthreads();

    const size_t vbase = (size_t)(b * SEQ) * 1536 + 1024 + g * 64;
    {
        const int d = t & 63;
        for (int j4 = (t >> 6) * 4; j4 < SEQ; j4 += 16) {
            ushort4 vv;
            vv.x = qkv[vbase + (size_t)(j4 + 0) * 1536 + d];
            vv.y = (j4 + 1 < SEQ) ? qkv[vbase + (size_t)(j4 + 1) * 1536 + d] : (ushort_t)0;
            vv.z = (j4 + 2 < SEQ) ? qkv[vbase + (size_t)(j4 + 2) * 1536 + d] : (ushort_t)0;
            vv.w = (j4 + 3 < SEQ) ? qkv[vbase + (size_t)(j4 + 3) * 1536 + d] : (ushort_t)0;
            *(ushort4*)(Vt + d * VSTR + j4) = vv;
        }
    }

    const ushort_t* gp = Pm + (size_t)bg * SP * PSTR + (size_t)q0 * PSTR;
    floatx4 acc[2][4];
    #pragma unroll
    for (int i = 0; i < 2; ++i)
        #pragma unroll
        for (int j = 0; j < 4; ++j)
            acc[i][j] = (floatx4){0.f, 0.f, 0.f, 0.f};

    for (int k0 = 0; k0 < PSTR; k0 += 32) {
        __syncthreads();
        #pragma unroll
        for (int rr = 0; rr < 2; ++rr) {
            const int row0 = (rr * 4 + w) * 16;
            if (row0 < cnt * 16)
                gl2lds16(gp + (size_t)(row0 + (lane >> 2)) * PSTR + k0 + (lane & 3) * 8,
                         As + row0 * 32);
        }
        __syncthreads();
        #pragma unroll
        for (int mi = 0; mi < 2; ++mi) {
            const int mfl = w + mi * 4;
            if (mfl >= cnt) break;
            const short8 af = *(const short8*)(As + (mfl * 16 + fr) * 32 + quad * 8);
            #pragma unroll
            for (int nf = 0; nf < 4; ++nf) {
                const short8 bfr = *(const short8*)(Vt + (nf * 16 + fr) * VSTR + k0 + quad * 8);
                acc[mi][nf] = __builtin_amdgcn_mfma_f32_16x16x32_bf16(af, bfr, acc[mi][nf], 0, 0, 0);
            }
        }
    }

    #pragma unroll
    for (int mi = 0; mi < 2; ++mi) {
        const int mfl = w + mi * 4;
        if (mfl >= cnt) break;
        #pragma unroll
        for (int rr = 0; rr < 4; ++rr) {
            const int i = (hf * 7 + mfl) * 16 + quad * 4 + rr;
            if (i < SEQ) {
                ushort_t* op = o + (size_t)(b * SEQ + i) * DIM + g * 64 + fr;
                #pragma unroll
                for (int nf = 0; nf < 4; ++nf)
                    op[nf * 16] = f2bf(acc[mi][nf][rr]);
            }
        }
    }
}

// ---------------------------------------------------------------------------
extern "C" void kernel_launch(void* const* d_in, const int* in_sizes, int n_in,
                              void* d_out, int out_size, void* d_ws, size_t ws_size,
                              hipStream_t stream)
{
    (void)in_sizes; (void)n_in; (void)out_size; (void)ws_size;

    const float* img       = (const float*)d_in[0];
    const float* patch_w   = (const float*)d_in[1];
    const float* patch_b   = (const float*)d_in[2];
    const float* cls_token = (const float*)d_in[3];
    const float* pos_emb   = (const float*)d_in[4];
    const float* ln1_w     = (const float*)d_in[5];
    const float* ln1_b     = (const float*)d_in[6];
    const float* qkv_w     = (const float*)d_in[7];
    const float* reattn_w  = (const float*)d_in[8];
    const float* reattn_lw = (const float*)d_in[9];
    const float* reattn_lb = (const float*)d_in[10];
    const float* out_w     = (const float*)d_in[11];
    const float* out_b     = (const float*)d_in[12];
    const float* ln2_w     = (const float*)d_in[13];
    const float* ln2_b     = (const float*)d_in[14];
    const float* ff1_w     = (const float*)d_in[15];
    const float* ff1_b     = (const float*)d_in[16];
    const float* ff2_w     = (const float*)d_in[17];
    const float* ff2_b     = (const float*)d_in[18];
    const float* head_lw   = (const float*)d_in[19];
    const float* head_lb   = (const float*)d_in[20];
    float* out = (float*)d_out;

    // workspace layout
    char* p = (char*)d_ws;
    float* x = (float*)p;            p += (size_t)MPAD * DIM * 4;
    ushort_t* hb = (ushort_t*)p;     p += (size_t)MPAD * DIM * 2;
    ushort_t* qkvb = (ushort_t*)p;   p += (size_t)MPAD * 1536 * 2;
    ushort_t* Pm = (ushort_t*)p;     p += (size_t)256 * SP * PSTR * 2;   // 23.9 MB
    ushort_t* midb = (ushort_t*)p;   p += (size_t)MPAD * MLPD * 2;       // 26.2 MB
    ushort_t* pcol = (ushort_t*)p;   p += (size_t)MPAD * PKD * 2;
    ushort_t* pwt  = (ushort_t*)p;   p += (size_t)DIM * PKD * 2;
    ushort_t* qkv_wt = (ushort_t*)p; p += (size_t)NDEPTH * 1536 * 512 * 2;
    ushort_t* out_wt = (ushort_t*)p; p += (size_t)NDEPTH * 512 * 512 * 2;
    ushort_t* ff1_wt = (ushort_t*)p; p += (size_t)NDEPTH * 2048 * 512 * 2;
    ushort_t* ff2_wt = (ushort_t*)p; p += (size_t)NDEPTH * 512 * 2048 * 2;

    // one-time weight prep
    wtrans_kernel<<<dim3(1536 / 32, 512 / 32, NDEPTH), 256, 0, stream>>>(qkv_w, qkv_wt, 512, 1536);
    wtrans_kernel<<<dim3(512 / 32, 512 / 32, NDEPTH), 256, 0, stream>>>(out_w, out_wt, 512, 512);
    wtrans_kernel<<<dim3(2048 / 32, 512 / 32, NDEPTH), 256, 0, stream>>>(ff1_w, ff1_wt, 512, 2048);
    wtrans_kernel<<<dim3(512 / 32, 2048 / 32, NDEPTH), 256, 0, stream>>>(ff2_w, ff2_wt, 2048, 512);
    pwt_kernel<<<DIM, 256, 0, stream>>>(patch_w, pwt);

    // patch embed = im2col + GEMM + pos add (+ layer-0 ln1)
    im2col_kernel<<<MPAD, 256, 0, stream>>>(img, pcol);
    gemm_bf16_kernel<64, 512, PKD, 3><<<dim3(DIM / 128, MPAD / 64), 256, 0, stream>>>(
        pcol, pwt, patch_b, nullptr, x);
    pos_add_ln_kernel<<<ROWS, 256, 0, stream>>>(x, cls_token, pos_emb, hb, ln1_w, ln1_b);

    for (int l = 0; l < NDEPTH; ++l) {
        if (l > 0)
            ln4_kernel<<<ROWS / 4, 256, 0, stream>>>(x, hb, ln1_w + l * DIM, ln1_b + l * DIM);
        gemm_bf16_kernel<128, 1536, 512, 0><<<dim3(1536 / 128, MPAD / 128), 256, 0, stream>>>(
            hb, qkv_wt + (size_t)l * 1536 * 512, nullptr, qkvb, nullptr);
        qkmix_kernel<<<dim3(13, BATCH), 256, 0, stream>>>(
            qkvb, reattn_w + l * 64, reattn_lw + l * 8, reattn_lb + l * 8, Pm);
        av_kernel<<<dim3(BATCH * NHEADS, 2), 256, 0, stream>>>(Pm, qkvb, hb);
        gemm_bf16_kernel<64, 512, 512, 1><<<dim3(DIM / 128, MPAD / 64), 256, 0, stream>>>(
            hb, out_wt + (size_t)l * 512 * 512, out_b + l * DIM, nullptr, x);
        ln4_kernel<<<ROWS / 4, 256, 0, stream>>>(x, hb, ln2_w + l * DIM, ln2_b + l * DIM);
        gemm_bf16_kernel<128, 2048, 512, 2><<<dim3(MLPD / 128, MPAD / 128), 256, 0, stream>>>(
            hb, ff1_wt + (size_t)l * 2048 * 512, ff1_b + l * MLPD, midb, nullptr);
        gemm_bf16_kernel<64, 512, 2048, 1><<<dim3(DIM / 128, MPAD / 64), 256, 0, stream>>>(
            midb, ff2_wt + (size_t)l * 512 * 2048, ff2_b + l * DIM, nullptr, x);
    }

    ln_kernel<<<BATCH, 256, 0, stream>>>(x, out, head_lw, head_lb, (size_t)SEQ * DIM, DIM);
}

// Round 7
// 2028.181 us; speedup vs baseline: 1.1905x; 1.1905x over previous
//
#include <hip/hip_runtime.h>
#include <math.h>

#define SEQ    197
#define BATCH  32
#define ROWS   (BATCH * SEQ)      // 6304
#define MPAD   6400               // padded row count
#define DIM    512
#define NHEADS 8
#define NDEPTH 12
#define MLPD   2048
#define PKD    448                // patch K padded (432 real), 7 x 64
#define SP     208                // padded seq for attention (13 x 16)
#define PSTR   224                // Pm col stride (7 x 32)
#define VSTR   228                // Vt LDS row stride
#define ASTR   40                 // av As LDS row stride (pad for banks)
#define EPSF   1e-5f

typedef unsigned short ushort_t;
typedef __attribute__((ext_vector_type(8))) short  short8;
typedef __attribute__((ext_vector_type(4))) float  floatx4;

__device__ __forceinline__ float bf2f(ushort_t u) {
    union { unsigned int i; float f; } v; v.i = ((unsigned int)u) << 16; return v.f;
}
__device__ __forceinline__ ushort_t f2bf(float f) {
    union { float f; unsigned int i; } v; v.f = f;
    unsigned int r = v.i + 0x7fffu + ((v.i >> 16) & 1u);
    return (ushort_t)(r >> 16);
}
__device__ __forceinline__ void gl2lds16(const ushort_t* g, ushort_t* l) {
    __builtin_amdgcn_global_load_lds(
        (const __attribute__((address_space(1))) unsigned int*)g,
        (__attribute__((address_space(3))) unsigned int*)l, 16, 0, 0);
}
__device__ __forceinline__ float gelu_tanh(float v) {
    const float y = 0.7978845608028654f * fmaf(0.044715f * v, v * v, v);
    const float e = __expf(-2.f * fabsf(y));
    const float th = copysignf((1.f - e) * __builtin_amdgcn_rcpf(1.f + e), y);
    return 0.5f * v * (1.f + th);
}

// ---------------------------------------------------------------------------
// Weight transpose + fp32->bf16: Wt[l][n][k] = bf16(W[l][k][n])
// ---------------------------------------------------------------------------
__global__ __launch_bounds__(256) void wtrans_kernel(
    const float* __restrict__ W, ushort_t* __restrict__ Wt, int K, int N)
{
    const int l = blockIdx.z;
    W  += (size_t)l * K * N;
    Wt += (size_t)l * K * N;
    const int n0 = blockIdx.x * 32;
    const int k0 = blockIdx.y * 32;
    const int t = threadIdx.x;

    __shared__ float tile[32][33];
    {
        const int row = t >> 3;
        const int cq  = (t & 7) * 4;
        const float4 v = *(const float4*)(W + (size_t)(k0 + row) * N + n0 + cq);
        tile[row][cq + 0] = v.x;
        tile[row][cq + 1] = v.y;
        tile[row][cq + 2] = v.z;
        tile[row][cq + 3] = v.w;
    }
    __syncthreads();
    {
        const int n  = t >> 3;
        const int kq = (t & 7) * 4;
        ushort4 o;
        o.x = f2bf(tile[kq + 0][n]);
        o.y = f2bf(tile[kq + 1][n]);
        o.z = f2bf(tile[kq + 2][n]);
        o.w = f2bf(tile[kq + 3][n]);
        *(ushort4*)(Wt + (size_t)(n0 + n) * K + k0 + kq) = o;
    }
}

// ---------------------------------------------------------------------------
// patch_w [432][512] -> pwt [512][448] bf16 (k >= 432 zero)
// ---------------------------------------------------------------------------
__global__ __launch_bounds__(256) void pwt_kernel(
    const float* __restrict__ pw, ushort_t* __restrict__ pwt)
{
    const int n = blockIdx.x;
    for (int k = threadIdx.x; k < PKD; k += 256)
        pwt[(size_t)n * PKD + k] = (k < 432) ? f2bf(pw[(size_t)k * DIM + n]) : (ushort_t)0;
}

// ---------------------------------------------------------------------------
// im2col: pcol[row][448] bf16.
// ---------------------------------------------------------------------------
__global__ __launch_bounds__(256) void im2col_kernel(
    const float* __restrict__ img, ushort_t* __restrict__ pcol)
{
    const int r = blockIdx.x;
    const int t = threadIdx.x;
    ushort_t* row = pcol + (size_t)r * PKD;
    const int b = r / SEQ;
    const int s = r - b * SEQ;
    const bool valid = (r < ROWS) && (s > 0);
    const int p = s - 1;
    const int gy = p / 14, gx = p - (p / 14) * 14;

    #pragma unroll
    for (int rep = 0; rep < 2; ++rep) {
        const int e = t + rep * 256;
        if (e >= PKD) break;
        float v = 0.f;
        if (valid && e < 432) {
            const int c = e / 144;
            const int rr = e - c * 144;
            const int fy = rr / 12, fx = rr - (rr / 12) * 12;
            const int py = gy * 8 - 2 + fy;
            const int px = gx * 8 - 2 + fx;
            if (py >= 0 && py < 112 && px >= 0 && px < 112)
                v = img[((size_t)(b * 3 + c) * 112 + py) * 112 + px];
        }
        row[e] = f2bf(v);
    }
}

// ---------------------------------------------------------------------------
// pos add + layer-0 ln1 fused: x = patch_acc (+cls) + pos; hb = bf16(LN(x))
// ---------------------------------------------------------------------------
__global__ __launch_bounds__(256) void pos_add_ln_kernel(
    float* __restrict__ x, const float* __restrict__ cls,
    const float* __restrict__ pos, ushort_t* __restrict__ hb,
    const float* __restrict__ g, const float* __restrict__ bta)
{
    const int r = blockIdx.x;
    const int t = threadIdx.x;
    const int b = r / SEQ;
    const int s = r - b * SEQ;
    float* xr = x + (size_t)r * DIM;
    const float* pr = pos + (size_t)s * DIM;
    float v0, v1;
    if (s == 0) {
        v0 = cls[t]       + pr[t];
        v1 = cls[t + 256] + pr[t + 256];
    } else {
        v0 = xr[t]       + pr[t];
        v1 = xr[t + 256] + pr[t + 256];
    }
    xr[t] = v0;
    xr[t + 256] = v1;
    float sm = v0 + v1;
    float ss = v0 * v0 + v1 * v1;
    #pragma unroll
    for (int off = 32; off > 0; off >>= 1) {
        sm += __shfl_xor(sm, off);
        ss += __shfl_xor(ss, off);
    }
    __shared__ float rs[4], rss[4];
    if ((t & 63) == 0) { rs[t >> 6] = sm; rss[t >> 6] = ss; }
    __syncthreads();
    sm = rs[0] + rs[1] + rs[2] + rs[3];
    ss = rss[0] + rss[1] + rss[2] + rss[3];
    const float mu  = sm * (1.f / 512.f);
    const float var = ss * (1.f / 512.f) - mu * mu;
    const float inv = rsqrtf(var + EPSF);
    ushort_t* op = hb + (size_t)r * DIM;
    op[t]       = f2bf((v0 - mu) * inv * g[t]       + bta[t]);
    op[t + 256] = f2bf((v1 - mu) * inv * g[t + 256] + bta[t + 256]);
}

// ---------------------------------------------------------------------------
// Fast LayerNorm: 4 rows/block, one wave per row, bf16 out.
// ---------------------------------------------------------------------------
__global__ __launch_bounds__(256) void ln4_kernel(
    const float* __restrict__ in, ushort_t* __restrict__ out,
    const float* __restrict__ g, const float* __restrict__ bta)
{
    const int t = threadIdx.x;
    const int w = t >> 6, lane = t & 63;
    const int r = blockIdx.x * 4 + w;
    const int off = lane * 8;
    const float* ip = in + (size_t)r * DIM + off;
    const float4 a = *(const float4*)ip;
    const float4 c = *(const float4*)(ip + 4);
    float s  = a.x + a.y + a.z + a.w + c.x + c.y + c.z + c.w;
    float ss = a.x*a.x + a.y*a.y + a.z*a.z + a.w*a.w + c.x*c.x + c.y*c.y + c.z*c.z + c.w*c.w;
    #pragma unroll
    for (int o = 32; o > 0; o >>= 1) {
        s  += __shfl_xor(s, o);
        ss += __shfl_xor(ss, o);
    }
    const float mu  = s * (1.f / 512.f);
    const float var = ss * (1.f / 512.f) - mu * mu;
    const float inv = rsqrtf(var + EPSF);
    const float4 g0 = *(const float4*)(g + off);
    const float4 g1 = *(const float4*)(g + off + 4);
    const float4 b0 = *(const float4*)(bta + off);
    const float4 b1 = *(const float4*)(bta + off + 4);
    ushort4 o0, o1;
    o0.x = f2bf((a.x - mu) * inv * g0.x + b0.x);
    o0.y = f2bf((a.y - mu) * inv * g0.y + b0.y);
    o0.z = f2bf((a.z - mu) * inv * g0.z + b0.z);
    o0.w = f2bf((a.w - mu) * inv * g0.w + b0.w);
    o1.x = f2bf((c.x - mu) * inv * g1.x + b1.x);
    o1.y = f2bf((c.y - mu) * inv * g1.y + b1.y);
    o1.z = f2bf((c.z - mu) * inv * g1.z + b1.z);
    o1.w = f2bf((c.w - mu) * inv * g1.w + b1.w);
    ushort_t* op = out + (size_t)r * DIM + off;
    *(ushort4*)op = o0;
    *(ushort4*)(op + 4) = o1;
}

// ---------------------------------------------------------------------------
// Row LayerNorm (final head LN; fp32 out)
// ---------------------------------------------------------------------------
__global__ __launch_bounds__(256) void ln_kernel(
    const float* __restrict__ in, float* __restrict__ out,
    const float* __restrict__ g, const float* __restrict__ bta,
    size_t in_stride, size_t out_stride)
{
    const int r = blockIdx.x;
    const int t = threadIdx.x;
    const float* ip = in + (size_t)r * in_stride;
    const float v0 = ip[t];
    const float v1 = ip[t + 256];
    float s = v0 + v1;
    float ss = v0 * v0 + v1 * v1;
    #pragma unroll
    for (int off = 32; off > 0; off >>= 1) {
        s  += __shfl_xor(s, off);
        ss += __shfl_xor(ss, off);
    }
    __shared__ float rs[4], rss[4];
    if ((t & 63) == 0) { rs[t >> 6] = s; rss[t >> 6] = ss; }
    __syncthreads();
    s  = rs[0] + rs[1] + rs[2] + rs[3];
    ss = rss[0] + rss[1] + rss[2] + rss[3];
    const float mu  = s * (1.f / 512.f);
    const float var = ss * (1.f / 512.f) - mu * mu;
    const float inv = rsqrtf(var + EPSF);
    float* op = out + (size_t)r * out_stride;
    op[t]       = (v0 - mu) * inv * g[t]       + bta[t];
    op[t + 256] = (v1 - mu) * inv * g[t + 256] + bta[t + 256];
}

// ---------------------------------------------------------------------------
// bf16 MFMA GEMM, compile-time shape. BK=64, XOR-swizzled LDS staging.
// MODE 0: Cb=bf16(acc+bias); 1: Cx+=acc+bias; 2: Cb=bf16(gelu); 3: Cx=acc+bias
// ---------------------------------------------------------------------------
template <int BM, int NN, int KK, int MODE>
__global__ __launch_bounds__(256) void gemm_bf16_kernel(
    const ushort_t* __restrict__ A, const ushort_t* __restrict__ Bt,
    const float* __restrict__ bias, ushort_t* __restrict__ Cb,
    float* __restrict__ Cx)
{
    constexpr int RA = BM / 4;
    constexpr int MI = BM / 32;
    __shared__ ushort_t As[BM * 64];
    __shared__ ushort_t Bs[128 * 64];
    const int t = threadIdx.x;
    const int l = t & 63;
    const int w = t >> 6;
    const int bm = blockIdx.y * BM;
    const int bn = blockIdx.x * 128;
    const int wm = (w & 1) * (BM / 2);
    const int wn = (w >> 1) * 64;

    const int srow = l >> 3;
    const int skw  = ((l & 7) ^ srow) * 8;
    const ushort_t* gA = A  + (size_t)(bm + w * RA + srow) * KK + skw;
    const ushort_t* gB = Bt + (size_t)(bn + w * 32 + srow) * KK + skw;

    floatx4 acc[MI][4];
    #pragma unroll
    for (int i = 0; i < MI; ++i)
        #pragma unroll
        for (int j = 0; j < 4; ++j)
            acc[i][j] = (floatx4){0.f, 0.f, 0.f, 0.f};

    const int fr = l & 15;
    const int quad = l >> 4;
    const int c0 = ((quad ^ (fr & 7)) * 8);

    #pragma unroll 4
    for (int k0 = 0; k0 < KK; k0 += 64) {
        #pragma unroll
        for (int jc = 0; jc < RA / 8; ++jc)
            gl2lds16(gA + (size_t)(jc * 8) * KK + k0, As + (w * RA + jc * 8) * 64);
        #pragma unroll
        for (int jc = 0; jc < 4; ++jc)
            gl2lds16(gB + (size_t)(jc * 8) * KK + k0, Bs + (w * 32 + jc * 8) * 64);
        __syncthreads();
        #pragma unroll
        for (int half = 0; half < 2; ++half) {
            const int co = c0 ^ (half * 32);
            short8 af[MI], bf4[4];
            #pragma unroll
            for (int i = 0; i < MI; ++i)
                af[i] = *(const short8*)(As + (wm + i * 16 + fr) * 64 + co);
            #pragma unroll
            for (int j = 0; j < 4; ++j)
                bf4[j] = *(const short8*)(Bs + (wn + j * 16 + fr) * 64 + co);
            #pragma unroll
            for (int i = 0; i < MI; ++i)
                #pragma unroll
                for (int j = 0; j < 4; ++j)
                    acc[i][j] = __builtin_amdgcn_mfma_f32_16x16x32_bf16(
                        af[i], bf4[j], acc[i][j], 0, 0, 0);
        }
        __syncthreads();
    }

    float bv[4];
    #pragma unroll
    for (int j = 0; j < 4; ++j)
        bv[j] = bias ? bias[bn + wn + j * 16 + fr] : 0.f;

    const int r0 = quad * 4;
    #pragma unroll
    for (int i = 0; i < MI; ++i)
        #pragma unroll
        for (int r = 0; r < 4; ++r) {
            const size_t row = (size_t)(bm + wm + i * 16 + r0 + r);
            if (MODE == 1) {
                float* cp = Cx + row * NN + bn + wn + fr;
                #pragma unroll
                for (int j = 0; j < 4; ++j)
                    cp[j * 16] += acc[i][j][r] + bv[j];
            } else if (MODE == 3) {
                float* cp = Cx + row * NN + bn + wn + fr;
                #pragma unroll
                for (int j = 0; j < 4; ++j)
                    cp[j * 16] = acc[i][j][r] + bv[j];
            } else if (MODE == 2) {
                ushort_t* cp = Cb + row * NN + bn + wn + fr;
                #pragma unroll
                for (int j = 0; j < 4; ++j)
                    cp[j * 16] = f2bf(gelu_tanh(acc[i][j][r] + bv[j]));
            } else {
                ushort_t* cp = Cb + row * NN + bn + wn + fr;
                #pragma unroll
                for (int j = 0; j < 4; ++j)
                    cp[j * 16] = f2bf(acc[i][j][r] + bv[j]);
            }
        }
}

// ---------------------------------------------------------------------------
// QK^T + softmax via MFMA. Block per (b,h, i-half). P fp32 [bh][208][208].
// Ks staged swizzled (2-way banks); Q frags read straight from global.
// ---------------------------------------------------------------------------
__global__ __launch_bounds__(256) void qk_softmax_kernel(
    const ushort_t* __restrict__ qkv, float* __restrict__ P)
{
    const int bh = blockIdx.x;
    const int hf = blockIdx.y;
    const int b = bh >> 3, h = bh & 7;
    const int t = threadIdx.x;
    const int w = t >> 6, lane = t & 63;
    const int fr = lane & 15, quad = lane >> 4;
    const int cnt = hf ? 6 : 7;

    __shared__ ushort_t Ks[SP * 64];

    const size_t base = (size_t)(b * SEQ) * 1536;
    // stage K_h swizzled: LDS[r][(c^(r&7))*8] = K[r][c*8..]
    for (int e = t; e < SP * 8; e += 256) {
        const int r = e >> 3;
        const int c = e & 7;
        *(short8*)(Ks + r * 64 + ((c ^ (r & 7)) * 8)) =
            *(const short8*)(qkv + base + (size_t)r * 1536 + 512 + h * 64 + c * 8);
    }
    __syncthreads();

    const int cx0 = (quad ^ (fr & 7)) * 8;
    const int cx1 = ((quad + 4) ^ (fr & 7)) * 8;

    #pragma unroll
    for (int mi = 0; mi < 2; ++mi) {
        const int mfl = w * 2 + mi;
        if (mfl >= cnt) break;
        const int mf = hf * 7 + mfl;
        const size_t qrow = base + (size_t)(mf * 16 + fr) * 1536 + h * 64;
        const short8 a0 = *(const short8*)(qkv + qrow + quad * 8);
        const short8 a1 = *(const short8*)(qkv + qrow + 32 + quad * 8);
        floatx4 acc[13];
        #pragma unroll
        for (int nf = 0; nf < 13; ++nf) {
            const ushort_t* kr = Ks + (nf * 16 + fr) * 64;
            const short8 b0 = *(const short8*)(kr + cx0);
            const short8 b1 = *(const short8*)(kr + cx1);
            floatx4 z = (floatx4){0.f, 0.f, 0.f, 0.f};
            z = __builtin_amdgcn_mfma_f32_16x16x32_bf16(a0, b0, z, 0, 0, 0);
            acc[nf] = __builtin_amdgcn_mfma_f32_16x16x32_bf16(a1, b1, z, 0, 0, 0);
        }
        #pragma unroll
        for (int rr = 0; rr < 4; ++rr) {
            const bool maskc = (fr >= 5);
            float mx = -1e30f;
            #pragma unroll
            for (int nf = 0; nf < 13; ++nf) {
                const float v = (nf == 12 && maskc) ? -1e30f : acc[nf][rr] * 0.125f;
                mx = fmaxf(mx, v);
            }
            #pragma unroll
            for (int off = 1; off < 16; off <<= 1) mx = fmaxf(mx, __shfl_xor(mx, off));
            float sum = 0.f;
            #pragma unroll
            for (int nf = 0; nf < 13; ++nf) {
                const float v = (nf == 12 && maskc) ? -1e30f : acc[nf][rr] * 0.125f;
                const float pe = __expf(v - mx);
                acc[nf][rr] = pe;
                sum += pe;
            }
            #pragma unroll
            for (int off = 1; off < 16; off <<= 1) sum += __shfl_xor(sum, off);
            const float inv = 1.f / sum;
            const int i = mf * 16 + quad * 4 + rr;
            float* prow = P + ((size_t)bh * SP + i) * SP + fr;
            #pragma unroll
            for (int nf = 0; nf < 13; ++nf)
                prow[nf * 16] = acc[nf][rr] * inv;
        }
    }
}

// ---------------------------------------------------------------------------
// Head mix + LN over heads: P fp32 -> Pm bf16 [b][g][208][224]. 4 rows/block.
// ---------------------------------------------------------------------------
__global__ __launch_bounds__(256) void mix_ln_kernel(
    const float* __restrict__ P, const float* __restrict__ rw,
    const float* __restrict__ lw, const float* __restrict__ lb,
    ushort_t* __restrict__ Pm)
{
    const int b = blockIdx.y;
    const int t = threadIdx.x;

    __shared__ float rws[64], lws[8], lbs[8];
    if (t < 64) rws[t] = rw[t];
    if (t < 8) { lws[t] = lw[t]; lbs[t] = lb[t]; }
    __syncthreads();

    for (int ii = 0; ii < 4; ++ii) {
        const int i = blockIdx.x * 4 + ii;
        if (i >= SEQ) break;
        float o[8];
        #pragma unroll
        for (int g = 0; g < 8; ++g) o[g] = 0.f;

        if (t < SEQ) {
            float a[8];
            #pragma unroll
            for (int h = 0; h < 8; ++h)
                a[h] = P[(((size_t)(b * 8 + h)) * SP + i) * SP + t];
            float m[8];
            float mu = 0.f;
            #pragma unroll
            for (int g = 0; g < 8; ++g) {
                float s = 0.f;
                #pragma unroll
                for (int h = 0; h < 8; ++h) s = fmaf(a[h], rws[h * 8 + g], s);
                m[g] = s;
                mu += s;
            }
            mu *= 0.125f;
            float var = 0.f;
            #pragma unroll
            for (int g = 0; g < 8; ++g) { const float d = m[g] - mu; var = fmaf(d, d, var); }
            var *= 0.125f;
            const float inv = rsqrtf(var + EPSF);
            #pragma unroll
            for (int g = 0; g < 8; ++g)
                o[g] = (m[g] - mu) * inv * lws[g] + lbs[g];
        }
        if (t < PSTR) {
            #pragma unroll
            for (int g = 0; g < 8; ++g)
                Pm[(((size_t)(b * 8 + g)) * SP + i) * PSTR + t] = f2bf(o[g]);
        }
    }
}

// ---------------------------------------------------------------------------
// AV via MFMA: block per (b,g, i-half). O = Pm (rows) @ V.
// As staged via registers into bank-padded LDS (stride 40).
// ---------------------------------------------------------------------------
__global__ __launch_bounds__(256) void av_kernel(
    const ushort_t* __restrict__ Pm, const ushort_t* __restrict__ qkv,
    ushort_t* __restrict__ o)
{
    const int bg = blockIdx.x;
    const int hf = blockIdx.y;
    const int b = bg >> 3, g = bg & 7;
    const int t = threadIdx.x;
    const int w = t >> 6, lane = t & 63;
    const int fr = lane & 15, quad = lane >> 4;
    const int cnt = hf ? 6 : 7;
    const int q0 = hf * 112;

    __shared__ ushort_t Vt[64 * VSTR];
    __shared__ ushort_t As[112 * ASTR];

    for (int e = t; e < 64 * VSTR / 4; e += 256)
        *(ushort4*)(Vt + e * 4) = (ushort4){0, 0, 0, 0};
    __syncthreads();

    const size_t vbase = (size_t)(b * SEQ) * 1536 + 1024 + g * 64;
    {
        const int d = t & 63;
        for (int j4 = (t >> 6) * 4; j4 < SEQ; j4 += 16) {
            ushort4 vv;
            vv.x = qkv[vbase + (size_t)(j4 + 0) * 1536 + d];
            vv.y = (j4 + 1 < SEQ) ? qkv[vbase + (size_t)(j4 + 1) * 1536 + d] : (ushort_t)0;
            vv.z = (j4 + 2 < SEQ) ? qkv[vbase + (size_t)(j4 + 2) * 1536 + d] : (ushort_t)0;
            vv.w = (j4 + 3 < SEQ) ? qkv[vbase + (size_t)(j4 + 3) * 1536 + d] : (ushort_t)0;
            *(ushort4*)(Vt + d * VSTR + j4) = vv;
        }
    }

    const ushort_t* gp = Pm + (size_t)bg * SP * PSTR + (size_t)q0 * PSTR;
    floatx4 acc[2][4];
    #pragma unroll
    for (int i = 0; i < 2; ++i)
        #pragma unroll
        for (int j = 0; j < 4; ++j)
            acc[i][j] = (floatx4){0.f, 0.f, 0.f, 0.f};

    const int nrows = cnt * 16;

    for (int k0 = 0; k0 < PSTR; k0 += 32) {
        __syncthreads();
        #pragma unroll
        for (int rep = 0; rep < 2; ++rep) {
            const int e = t + rep * 256;
            const int r = e >> 2;
            const int c = e & 3;
            if (r < nrows) {
                const short8 v = *(const short8*)(gp + (size_t)r * PSTR + k0 + c * 8);
                *(short8*)(As + r * ASTR + c * 8) = v;
            }
        }
        __syncthreads();
        #pragma unroll
        for (int mi = 0; mi < 2; ++mi) {
            const int mfl = w + mi * 4;
            if (mfl >= cnt) break;
            const short8 af = *(const short8*)(As + (mfl * 16 + fr) * ASTR + quad * 8);
            #pragma unroll
            for (int nf = 0; nf < 4; ++nf) {
                const short8 bfr = *(const short8*)(Vt + (nf * 16 + fr) * VSTR + k0 + quad * 8);
                acc[mi][nf] = __builtin_amdgcn_mfma_f32_16x16x32_bf16(af, bfr, acc[mi][nf], 0, 0, 0);
            }
        }
    }

    #pragma unroll
    for (int mi = 0; mi < 2; ++mi) {
        const int mfl = w + mi * 4;
        if (mfl >= cnt) break;
        #pragma unroll
        for (int rr = 0; rr < 4; ++rr) {
            const int i = (hf * 7 + mfl) * 16 + quad * 4 + rr;
            if (i < SEQ) {
                ushort_t* op = o + (size_t)(b * SEQ + i) * DIM + g * 64 + fr;
                #pragma unroll
                for (int nf = 0; nf < 4; ++nf)
                    op[nf * 16] = f2bf(acc[mi][nf][rr]);
            }
        }
    }
}

// ---------------------------------------------------------------------------
extern "C" void kernel_launch(void* const* d_in, const int* in_sizes, int n_in,
                              void* d_out, int out_size, void* d_ws, size_t ws_size,
                              hipStream_t stream)
{
    (void)in_sizes; (void)n_in; (void)out_size; (void)ws_size;

    const float* img       = (const float*)d_in[0];
    const float* patch_w   = (const float*)d_in[1];
    const float* patch_b   = (const float*)d_in[2];
    const float* cls_token = (const float*)d_in[3];
    const float* pos_emb   = (const float*)d_in[4];
    const float* ln1_w     = (const float*)d_in[5];
    const float* ln1_b     = (const float*)d_in[6];
    const float* qkv_w     = (const float*)d_in[7];
    const float* reattn_w  = (const float*)d_in[8];
    const float* reattn_lw = (const float*)d_in[9];
    const float* reattn_lb = (const float*)d_in[10];
    const float* out_w     = (const float*)d_in[11];
    const float* out_b     = (const float*)d_in[12];
    const float* ln2_w     = (const float*)d_in[13];
    const float* ln2_b     = (const float*)d_in[14];
    const float* ff1_w     = (const float*)d_in[15];
    const float* ff1_b     = (const float*)d_in[16];
    const float* ff2_w     = (const float*)d_in[17];
    const float* ff2_b     = (const float*)d_in[18];
    const float* head_lw   = (const float*)d_in[19];
    const float* head_lb   = (const float*)d_in[20];
    float* out = (float*)d_out;

    // workspace layout
    char* p = (char*)d_ws;
    float* x = (float*)p;            p += (size_t)MPAD * DIM * 4;
    ushort_t* hb = (ushort_t*)p;     p += (size_t)MPAD * DIM * 2;
    ushort_t* qkvb = (ushort_t*)p;   p += (size_t)MPAD * 1536 * 2;
    char* big = p;                   // P (44.3MB) + Pm (23.9MB); midb aliases P
    float* P = (float*)big;
    ushort_t* Pm = (ushort_t*)(big + (size_t)256 * SP * SP * 4);
    ushort_t* midb = (ushort_t*)big;
    p += (size_t)256 * SP * SP * 4 + (size_t)256 * SP * PSTR * 2;
    ushort_t* pcol = (ushort_t*)p;   p += (size_t)MPAD * PKD * 2;
    ushort_t* pwt  = (ushort_t*)p;   p += (size_t)DIM * PKD * 2;
    ushort_t* qkv_wt = (ushort_t*)p; p += (size_t)NDEPTH * 1536 * 512 * 2;
    ushort_t* out_wt = (ushort_t*)p; p += (size_t)NDEPTH * 512 * 512 * 2;
    ushort_t* ff1_wt = (ushort_t*)p; p += (size_t)NDEPTH * 2048 * 512 * 2;
    ushort_t* ff2_wt = (ushort_t*)p; p += (size_t)NDEPTH * 512 * 2048 * 2;

    // one-time weight prep
    wtrans_kernel<<<dim3(1536 / 32, 512 / 32, NDEPTH), 256, 0, stream>>>(qkv_w, qkv_wt, 512, 1536);
    wtrans_kernel<<<dim3(512 / 32, 512 / 32, NDEPTH), 256, 0, stream>>>(out_w, out_wt, 512, 512);
    wtrans_kernel<<<dim3(2048 / 32, 512 / 32, NDEPTH), 256, 0, stream>>>(ff1_w, ff1_wt, 512, 2048);
    wtrans_kernel<<<dim3(512 / 32, 2048 / 32, NDEPTH), 256, 0, stream>>>(ff2_w, ff2_wt, 2048, 512);
    pwt_kernel<<<DIM, 256, 0, stream>>>(patch_w, pwt);

    // patch embed = im2col + GEMM + pos add (+ layer-0 ln1)
    im2col_kernel<<<MPAD, 256, 0, stream>>>(img, pcol);
    gemm_bf16_kernel<64, 512, PKD, 3><<<dim3(DIM / 128, MPAD / 64), 256, 0, stream>>>(
        pcol, pwt, patch_b, nullptr, x);
    pos_add_ln_kernel<<<ROWS, 256, 0, stream>>>(x, cls_token, pos_emb, hb, ln1_w, ln1_b);

    for (int l = 0; l < NDEPTH; ++l) {
        if (l > 0)
            ln4_kernel<<<ROWS / 4, 256, 0, stream>>>(x, hb, ln1_w + l * DIM, ln1_b + l * DIM);
        gemm_bf16_kernel<128, 1536, 512, 0><<<dim3(1536 / 128, MPAD / 128), 256, 0, stream>>>(
            hb, qkv_wt + (size_t)l * 1536 * 512, nullptr, qkvb, nullptr);
        qk_softmax_kernel<<<dim3(BATCH * NHEADS, 2), 256, 0, stream>>>(qkvb, P);
        mix_ln_kernel<<<dim3(50, BATCH), 256, 0, stream>>>(
            P, reattn_w + l * 64, reattn_lw + l * 8, reattn_lb + l * 8, Pm);
        av_kernel<<<dim3(BATCH * NHEADS, 2), 256, 0, stream>>>(Pm, qkvb, hb);
        gemm_bf16_kernel<64, 512, 512, 1><<<dim3(DIM / 128, MPAD / 64), 256, 0, stream>>>(
            hb, out_wt + (size_t)l * 512 * 512, out_b + l * DIM, nullptr, x);
        ln4_kernel<<<ROWS / 4, 256, 0, stream>>>(x, hb, ln2_w + l * DIM, ln2_b + l * DIM);
        gemm_bf16_kernel<128, 2048, 512, 2><<<dim3(MLPD / 128, MPAD / 128), 256, 0, stream>>>(
            hb, ff1_wt + (size_t)l * 2048 * 512, ff1_b + l * MLPD, midb, nullptr);
        gemm_bf16_kernel<64, 512, 2048, 1><<<dim3(DIM / 128, MPAD / 64), 256, 0, stream>>>(
            midb, ff2_wt + (size_t)l * 512 * 2048, ff2_b + l * DIM, nullptr, x);
    }

    ln_kernel<<<BATCH, 256, 0, stream>>>(x, out, head_lw, head_lb, (size_t)SEQ * DIM, DIM);
}